// Round 3
// baseline (305.399 us; speedup 1.0000x reference)
//
#include <hip/hip_runtime.h>
#include <stdint.h>

#define BTOK 32768
#define DIN 256
#define DHID 512
#define DOUT 256
#define NEXP 16

typedef __attribute__((ext_vector_type(8))) short bf16x8;
typedef __attribute__((ext_vector_type(4))) float f32x4;

__device__ __forceinline__ unsigned short f2bf(float f){
  unsigned u = __builtin_bit_cast(unsigned, f);
  u = u + 0x7FFFu + ((u >> 16) & 1u);      // RNE, finite inputs only
  return (unsigned short)(u >> 16);
}
__device__ __forceinline__ float bf2f(unsigned short h){
  return __builtin_bit_cast(float, (unsigned)h << 16);
}

// ---------------- transpose + f32->bf16 convert:  src[e][R][C] -> dst[e][C][R]
__global__ __launch_bounds__(256) void transpose_cvt(const float* __restrict__ src,
                                                     unsigned short* __restrict__ dst,
                                                     int R, int C){
  __shared__ float t[32][33];
  int e = blockIdx.z, r0 = blockIdx.y * 32, c0 = blockIdx.x * 32;
  int lx = threadIdx.x & 31, ly = threadIdx.x >> 5;
  const float* s = src + (size_t)e * R * C;
  unsigned short* d = dst + (size_t)e * R * C;
#pragma unroll
  for (int i = 0; i < 4; i++){ int r = ly + i * 8; t[r][lx] = s[(size_t)(r0 + r) * C + c0 + lx]; }
  __syncthreads();
#pragma unroll
  for (int i = 0; i < 4; i++){ int r = ly + i * 8; d[(size_t)(c0 + r) * R + r0 + lx] = f2bf(t[lx][r]); }
}

// ---------------- gating: 512 blocks x 64 tokens; LDS-aggregated histogram
__global__ __launch_bounds__(256) void gating_kernel(const float* __restrict__ x,
                                                     const float* __restrict__ Wg,
                                                     const float* __restrict__ bg,
                                                     unsigned short* __restrict__ x_bf,
                                                     int* __restrict__ top_idx,
                                                     float* __restrict__ top_w,
                                                     int* __restrict__ counts){
  __shared__ float WgT[16][256];   // transposed gate weights
  __shared__ int hist[16];
  int tid = threadIdx.x;
#pragma unroll
  for (int j = 0; j < 4; j++){     // coalesced: thread reads 64B contiguous
    float4 wv = *(const float4*)(Wg + tid * 16 + j * 4);
    WgT[j * 4 + 0][tid] = wv.x; WgT[j * 4 + 1][tid] = wv.y;
    WgT[j * 4 + 2][tid] = wv.z; WgT[j * 4 + 3][tid] = wv.w;
  }
  if (tid < 16) hist[tid] = 0;
  __syncthreads();
  int wid = tid >> 6, lane = tid & 63;

  for (int t = 0; t < 16; t++){
    int tok = blockIdx.x * 64 + wid * 16 + t;
    const float4 xv = *(const float4*)(x + (size_t)tok * DIN + lane * 4);
    ushort4 xb; xb.x = f2bf(xv.x); xb.y = f2bf(xv.y); xb.z = f2bf(xv.z); xb.w = f2bf(xv.w);
    *(ushort4*)(x_bf + (size_t)tok * DIN + lane * 4) = xb;
    float logit[16];
#pragma unroll
    for (int e = 0; e < 16; e++){
      const float4 wv = *(const float4*)(&WgT[e][lane * 4]);
      float v = xv.x * wv.x + xv.y * wv.y + xv.z * wv.z + xv.w * wv.w;
#pragma unroll
      for (int off = 32; off; off >>= 1) v += __shfl_xor(v, off, 64);
      logit[e] = v + bg[e];
    }
    if (lane == 0){
      int i1 = 0; float v1 = logit[0];
#pragma unroll
      for (int e = 1; e < 16; e++) if (logit[e] > v1){ v1 = logit[e]; i1 = e; }
      int i2 = -1; float v2 = -3.4e38f;
#pragma unroll
      for (int e = 0; e < 16; e++) if (e != i1 && logit[e] > v2){ v2 = logit[e]; i2 = e; }
      float tt = expf(v2 - v1);               // <= 1
      float w1 = 1.0f / (1.0f + tt);
      float w2 = tt / (1.0f + tt);
      top_idx[tok * 2] = i1; top_idx[tok * 2 + 1] = i2;
      top_w[tok * 2] = w1;  top_w[tok * 2 + 1] = w2;
      atomicAdd(&hist[i1], 1); atomicAdd(&hist[i2], 1);   // LDS atomics
    }
  }
  __syncthreads();
  if (tid < 16) atomicAdd(&counts[tid], hist[tid]);       // 16 global atomics/block
}

// ---------------- prefix sum + block map (one wave, lane-parallel)
__global__ void prefix_kernel(const int* __restrict__ counts, int* __restrict__ offsets,
                              int* __restrict__ cursor, int* __restrict__ bm_e,
                              int* __restrict__ bm_start, int* __restrict__ bm_end,
                              int* __restrict__ nblocks){
  int lane = threadIdx.x & 63;
  if (lane < 16){
    int c = counts[lane];
    int s = c;                                   // inclusive scan of counts
#pragma unroll
    for (int off = 1; off < 16; off <<= 1){
      int o = __shfl_up(s, off, 64);
      if (lane >= off) s += o;
    }
    int start = s - c;                           // exclusive
    offsets[lane] = start; cursor[lane] = start;
    int nb = (c + 63) >> 6;
    int t = nb;                                  // inclusive scan of block counts
#pragma unroll
    for (int off = 1; off < 16; off <<= 1){
      int o = __shfl_up(t, off, 64);
      if (lane >= off) t += o;
    }
    int bstart = t - nb;
    for (int b = 0; b < nb; b++){
      bm_e[bstart + b] = lane;
      bm_start[bstart + b] = start + b * 64;
      bm_end[bstart + b] = start + c;
    }
    if (lane == 15) nblocks[0] = t;
  }
}

// ---------------- scatter: block-aggregated chunk reservation, LDS ranks
__global__ __launch_bounds__(256) void scatter_kernel(const int* __restrict__ top_idx,
                                                      const float* __restrict__ top_w,
                                                      int* __restrict__ cursor,
                                                      int* __restrict__ pair_tok,
                                                      float* __restrict__ pair_w,
                                                      int* __restrict__ pair_slot){
  __shared__ int hist[16], base[16], rank[16];
  int tid = threadIdx.x;
  if (tid < 16){ hist[tid] = 0; rank[tid] = 0; }
  __syncthreads();
  int t = blockIdx.x * 256 + tid;
  int e0 = top_idx[t * 2], e1 = top_idx[t * 2 + 1];
  float w0 = top_w[t * 2], w1 = top_w[t * 2 + 1];
  atomicAdd(&hist[e0], 1); atomicAdd(&hist[e1], 1);
  __syncthreads();
  if (tid < 16) base[tid] = atomicAdd(&cursor[tid], hist[tid]);  // 16 global atomics/block
  __syncthreads();
  int r0 = atomicAdd(&rank[e0], 1);
  int p0 = base[e0] + r0;
  pair_tok[p0] = t; pair_w[p0] = w0; pair_slot[t * 2] = p0;
  int r1 = atomicAdd(&rank[e1], 1);
  int p1 = base[e1] + r1;
  pair_tok[p1] = t; pair_w[p1] = w1; pair_slot[t * 2 + 1] = p1;
}

// ---------------- fused 2-layer expert MLP, 64 pairs/block, 4 waves
// phase A: W1 B-fragments straight from global (L1/L2-hot), NO barriers
// hs double-buffered -> ONE barrier per 64-hid chunk
__global__ __launch_bounds__(256, 3) void moe_gemm_kernel(
    const unsigned short* __restrict__ x_bf,   // [B][256]
    const unsigned short* __restrict__ W1t,    // [E][512][256]  (n-major)
    const unsigned short* __restrict__ W2t,    // [E][256][512]  (n-major)
    const float* __restrict__ b1,              // [E][512]
    const float* __restrict__ b2,              // [E][256]
    const int* __restrict__ pair_tok, const float* __restrict__ pair_w,
    const int* __restrict__ bm_e, const int* __restrict__ bm_start,
    const int* __restrict__ bm_end, const int* __restrict__ nblocks,
    unsigned short* __restrict__ ypair){       // [65536][256] bf16
  int bid = blockIdx.x;
  if (bid >= nblocks[0]) return;
  int e = bm_e[bid], rs = bm_start[bid], re = bm_end[bid];

  __shared__ unsigned short xs[64 * 256];      // 32KB, swizzled
  __shared__ unsigned short hs[2][64 * 64];    // 16KB, swizzled [m][k], double-buffered
  __shared__ int   tokS[64];
  __shared__ float wS[64];
  char* xsb = (char*)xs;

  int tid = threadIdx.x;
  if (tid < 64){
    int g = rs + tid;
    bool valid = g < re;
    tokS[tid] = valid ? pair_tok[g] : 0;
    wS[tid]   = valid ? pair_w[g] : 0.0f;
  }
  __syncthreads();

  // stage x tile (64 rows x 256 bf16), XOR-swizzled rows of 512B
#pragma unroll
  for (int it = 0; it < 8; it++){
    int flat = it * 256 + tid;
    int row = flat >> 5, ch = flat & 31;
    uint4 v = *(const uint4*)(x_bf + (size_t)tokS[row] * DIN + ch * 8);
    *(uint4*)(xsb + ((row * 512 + ch * 16) ^ ((row & 7) << 4))) = v;
  }
  __syncthreads();

  int wid = tid >> 6, lane = tid & 63, lr = lane & 15, lh = lane >> 4;
  int arow = 16 * wid + lr;
  f32x4 acc[4][4];
#pragma unroll
  for (int i = 0; i < 4; i++)
#pragma unroll
    for (int j = 0; j < 4; j++) acc[i][j] = (f32x4){0.f, 0.f, 0.f, 0.f};

  const unsigned short* W1e = W1t + (size_t)e * DHID * DIN;
  const unsigned short* W2e = W2t + (size_t)e * DOUT * DHID;

  for (int c = 0; c < 8; c++){             // hid chunks of 64
    f32x4 hacc[4];
#pragma unroll
    for (int i = 0; i < 4; i++) hacc[i] = (f32x4){0.f, 0.f, 0.f, 0.f};
    const unsigned short* W1c = W1e + (size_t)c * 64 * DIN;

    // ---- phase A: h-chunk = x @ W1c, B-fragments from global, zero barriers
#pragma unroll
    for (int kb = 0; kb < 4; kb++){
      bf16x8 wb[2][4];
#pragma unroll
      for (int ks = 0; ks < 2; ks++)
#pragma unroll
        for (int nt = 0; nt < 4; nt++)
          wb[ks][nt] = *(const bf16x8*)(W1c + (size_t)(nt * 16 + lr) * DIN + kb * 64 + ks * 32 + lh * 8);
#pragma unroll
      for (int ks = 0; ks < 2; ks++){
        int kk = kb * 64 + ks * 32 + lh * 8;
        bf16x8 a = *(const bf16x8*)(xsb + ((arow * 512 + kk * 2) ^ ((arow & 7) << 4)));
#pragma unroll
        for (int nt = 0; nt < 4; nt++)
          hacc[nt] = __builtin_amdgcn_mfma_f32_16x16x32_bf16(a, wb[ks][nt], hacc[nt], 0, 0, 0);
      }
    }

    // ---- prefetch W2 fragments for this chunk (independent of hs barrier)
    bf16x8 w2f[2][4];
#pragma unroll
    for (int ks = 0; ks < 2; ks++)
#pragma unroll
      for (int nt = 0; nt < 4; nt++)
        w2f[ks][nt] = *(const bf16x8*)(W2e + (size_t)(64 * wid + nt * 16 + lr) * DHID + c * 64 + ks * 32 + lh * 8);

    // ---- epilogue A: relu(h + b1) -> bf16 -> hs[c&1]
    char* hcur = (char*)hs[c & 1];
#pragma unroll
    for (int nt = 0; nt < 4; nt++){
      float b1v = b1[e * DHID + c * 64 + nt * 16 + lr];
#pragma unroll
      for (int r = 0; r < 4; r++){
        int hrow = 16 * wid + lh * 4 + r;
        float v = hacc[nt][r] + b1v;
        v = fmaxf(v, 0.0f);
        int hcol = nt * 16 + lr;
        *(unsigned short*)(hcur + ((hrow * 128 + hcol * 2) ^ ((hrow & 7) << 4))) = f2bf(v);
      }
    }
    __syncthreads();                      // the ONLY barrier per chunk

    // ---- phase B: y += h[64x64] @ W2chunk ; wave w owns output cols 64w..64w+63
#pragma unroll
    for (int ks = 0; ks < 2; ks++){
      bf16x8 af[4];
#pragma unroll
      for (int mt = 0; mt < 4; mt++){
        int hr = mt * 16 + lr, hk = ks * 32 + lh * 8;
        af[mt] = *(const bf16x8*)(hcur + ((hr * 128 + hk * 2) ^ ((hr & 7) << 4)));
      }
#pragma unroll
      for (int nt = 0; nt < 4; nt++)
#pragma unroll
        for (int mt = 0; mt < 4; mt++)
          acc[mt][nt] = __builtin_amdgcn_mfma_f32_16x16x32_bf16(af[mt], w2f[ks][nt], acc[mt][nt], 0, 0, 0);
    }
  }

  // epilogue: fold gate weight + b2, store per-pair bf16 rows
#pragma unroll
  for (int nt = 0; nt < 4; nt++){
    int col = 64 * wid + nt * 16 + lr;
    float b2v = b2[e * DOUT + col];
#pragma unroll
    for (int mt = 0; mt < 4; mt++){
#pragma unroll
      for (int r = 0; r < 4; r++){
        int row = mt * 16 + lh * 4 + r;
        int prow = rs + row;
        if (prow < re){
          float val = wS[row] * (acc[mt][nt][r] + b2v);
          ypair[(size_t)prow * DOUT + col] = f2bf(val);
        }
      }
    }
  }
}

// ---------------- combine two pair rows per token
__global__ __launch_bounds__(256) void combine_kernel(const unsigned short* __restrict__ yp,
                                                      const int* __restrict__ pair_slot,
                                                      float* __restrict__ out){
  int idx = blockIdx.x * 256 + threadIdx.x;   // BTOK*64 threads, 4 cols each
  int t = idx >> 6;
  int c4 = (idx & 63) << 2;
  int s0 = pair_slot[t * 2], s1 = pair_slot[t * 2 + 1];
  ushort4 a = *(const ushort4*)(yp + (size_t)s0 * DOUT + c4);
  ushort4 b = *(const ushort4*)(yp + (size_t)s1 * DOUT + c4);
  float4 o;
  o.x = bf2f(a.x) + bf2f(b.x);
  o.y = bf2f(a.y) + bf2f(b.y);
  o.z = bf2f(a.z) + bf2f(b.z);
  o.w = bf2f(a.w) + bf2f(b.w);
  *(float4*)(out + (size_t)t * DOUT + c4) = o;
}

extern "C" void kernel_launch(void* const* d_in, const int* in_sizes, int n_in,
                              void* d_out, int out_size, void* d_ws, size_t ws_size,
                              hipStream_t stream){
  (void)in_sizes; (void)n_in; (void)out_size; (void)ws_size;
  const float* x  = (const float*)d_in[0];
  const float* Wg = (const float*)d_in[1];
  const float* bg = (const float*)d_in[2];
  const float* W1 = (const float*)d_in[3];
  const float* b1 = (const float*)d_in[4];
  const float* W2 = (const float*)d_in[5];
  const float* b2 = (const float*)d_in[6];
  float* out = (float*)d_out;
  char* ws = (char*)d_ws;

  unsigned short* x_bf  = (unsigned short*)(ws);                 // 16,777,216
  unsigned short* W1t   = (unsigned short*)(ws + 16777216);      //  4,194,304
  unsigned short* W2t   = (unsigned short*)(ws + 20971520);      //  4,194,304
  unsigned short* ypair = (unsigned short*)(ws + 25165824);      // 33,554,432
  int*   top_idx  = (int*)  (ws + 58720256);
  float* top_w    = (float*)(ws + 58982400);
  int*   pair_tok = (int*)  (ws + 59244544);
  float* pair_w   = (float*)(ws + 59506688);
  int*   pair_slot= (int*)  (ws + 59768832);
  int*   counts   = (int*)  (ws + 60030976);
  int*   offsets  = (int*)  (ws + 60031040);
  int*   cursor   = (int*)  (ws + 60031104);
  int*   nblocks  = (int*)  (ws + 60031168);
  int*   bm_e     = (int*)  (ws + 60031232);
  int*   bm_start = (int*)  (ws + 60035584);
  int*   bm_end   = (int*)  (ws + 60039936);

  hipMemsetAsync(counts, 0, 64, stream);
  transpose_cvt<<<dim3(16, 8, 16), 256, 0, stream>>>(W1, W1t, 256, 512);
  transpose_cvt<<<dim3(8, 16, 16), 256, 0, stream>>>(W2, W2t, 512, 256);
  gating_kernel<<<512, 256, 0, stream>>>(x, Wg, bg, x_bf, top_idx, top_w, counts);
  prefix_kernel<<<1, 64, 0, stream>>>(counts, offsets, cursor, bm_e, bm_start, bm_end, nblocks);
  scatter_kernel<<<128, 256, 0, stream>>>(top_idx, top_w, cursor, pair_tok, pair_w, pair_slot);
  moe_gemm_kernel<<<1040, 256, 0, stream>>>(x_bf, W1t, W2t, b1, b2, pair_tok, pair_w,
                                            bm_e, bm_start, bm_end, nblocks, ypair);
  combine_kernel<<<8192, 256, 0, stream>>>(ypair, pair_slot, out);
}

// Round 4
// 186.147 us; speedup vs baseline: 1.6406x; 1.6406x over previous
//
#include <hip/hip_runtime.h>
#include <stdint.h>

#define BTOK 32768
#define DIN 256
#define DHID 512
#define DOUT 256
#define NEXP 16
#define BM 128
#define SLOTS 80

typedef __attribute__((ext_vector_type(8))) short bf16x8;
typedef __attribute__((ext_vector_type(4))) float f32x4;

__device__ __forceinline__ unsigned short f2bf(float f){
  unsigned u = __builtin_bit_cast(unsigned, f);
  u = u + 0x7FFFu + ((u >> 16) & 1u);      // RNE, finite inputs only
  return (unsigned short)(u >> 16);
}
__device__ __forceinline__ float bf2f(unsigned short h){
  return __builtin_bit_cast(float, (unsigned)h << 16);
}

__device__ __forceinline__ void gload16(const void* g, void* l){
  __builtin_amdgcn_global_load_lds((const __attribute__((address_space(1))) unsigned int*)g,
                                   (__attribute__((address_space(3))) unsigned int*)l, 16, 0, 0);
}

// ---------------- transpose + f32->bf16 convert:  src[e][R][C] -> dst[e][C][R]
__global__ __launch_bounds__(256) void transpose_cvt(const float* __restrict__ src,
                                                     unsigned short* __restrict__ dst,
                                                     int R, int C){
  __shared__ float t[32][33];
  int e = blockIdx.z, r0 = blockIdx.y * 32, c0 = blockIdx.x * 32;
  int lx = threadIdx.x & 31, ly = threadIdx.x >> 5;
  const float* s = src + (size_t)e * R * C;
  unsigned short* d = dst + (size_t)e * R * C;
#pragma unroll
  for (int i = 0; i < 4; i++){ int r = ly + i * 8; t[r][lx] = s[(size_t)(r0 + r) * C + c0 + lx]; }
  __syncthreads();
#pragma unroll
  for (int i = 0; i < 4; i++){ int r = ly + i * 8; d[(size_t)(c0 + r) * R + r0 + lx] = f2bf(t[lx][r]); }
}

// ---------------- gating: 512 blocks x 64 tokens; LDS-aggregated histogram
__global__ __launch_bounds__(256) void gating_kernel(const float* __restrict__ x,
                                                     const float* __restrict__ Wg,
                                                     const float* __restrict__ bg,
                                                     unsigned short* __restrict__ x_bf,
                                                     int* __restrict__ top_idx,
                                                     float* __restrict__ top_w,
                                                     int* __restrict__ counts){
  __shared__ float WgT[16][256];
  __shared__ int hist[16];
  int tid = threadIdx.x;
#pragma unroll
  for (int j = 0; j < 4; j++){
    float4 wv = *(const float4*)(Wg + tid * 16 + j * 4);
    WgT[j * 4 + 0][tid] = wv.x; WgT[j * 4 + 1][tid] = wv.y;
    WgT[j * 4 + 2][tid] = wv.z; WgT[j * 4 + 3][tid] = wv.w;
  }
  if (tid < 16) hist[tid] = 0;
  __syncthreads();
  int wid = tid >> 6, lane = tid & 63;

  for (int t = 0; t < 16; t++){
    int tok = blockIdx.x * 64 + wid * 16 + t;
    const float4 xv = *(const float4*)(x + (size_t)tok * DIN + lane * 4);
    ushort4 xb; xb.x = f2bf(xv.x); xb.y = f2bf(xv.y); xb.z = f2bf(xv.z); xb.w = f2bf(xv.w);
    *(ushort4*)(x_bf + (size_t)tok * DIN + lane * 4) = xb;
    float logit[16];
#pragma unroll
    for (int e = 0; e < 16; e++){
      const float4 wv = *(const float4*)(&WgT[e][lane * 4]);
      float v = xv.x * wv.x + xv.y * wv.y + xv.z * wv.z + xv.w * wv.w;
#pragma unroll
      for (int off = 32; off; off >>= 1) v += __shfl_xor(v, off, 64);
      logit[e] = v + bg[e];
    }
    if (lane == 0){
      int i1 = 0; float v1 = logit[0];
#pragma unroll
      for (int e = 1; e < 16; e++) if (logit[e] > v1){ v1 = logit[e]; i1 = e; }
      int i2 = -1; float v2 = -3.4e38f;
#pragma unroll
      for (int e = 0; e < 16; e++) if (e != i1 && logit[e] > v2){ v2 = logit[e]; i2 = e; }
      float tt = expf(v2 - v1);
      float w1 = 1.0f / (1.0f + tt);
      float w2 = tt / (1.0f + tt);
      top_idx[tok * 2] = i1; top_idx[tok * 2 + 1] = i2;
      top_w[tok * 2] = w1;  top_w[tok * 2 + 1] = w2;
      atomicAdd(&hist[i1], 1); atomicAdd(&hist[i2], 1);
    }
  }
  __syncthreads();
  if (tid < 16) atomicAdd(&counts[tid], hist[tid]);
}

// ---------------- prefix sum + XCD-affine block map (one wave)
// expert e's blocks land at bm[(e&7)*SLOTS + sbase..], so blockIdx%8 == e%8
__global__ void prefix_kernel(const int* __restrict__ counts, int* __restrict__ offsets,
                              int* __restrict__ cursor, int* __restrict__ bm_e,
                              int* __restrict__ bm_start, int* __restrict__ bm_end){
  int lane = threadIdx.x & 63;
  int c = (lane < 16) ? counts[lane] : 0;
  int s = c;
#pragma unroll
  for (int off = 1; off < 16; off <<= 1){ int o = __shfl_up(s, off, 64); if (lane >= off) s += o; }
  int start = s - c;
  if (lane < 16){ offsets[lane] = start; cursor[lane] = start; }
  int nb = (c + BM - 1) >> 7;
  int nb_partner = __shfl(nb, lane ^ 8, 64);
  if (lane < 8){
    int filled = nb + nb_partner;
    if (filled > SLOTS) filled = SLOTS;
    for (int i = filled; i < SLOTS; i++) bm_e[lane * SLOTS + i] = -1;
  }
  if (lane < 16){
    int sbase = (lane < 8) ? 0 : nb_partner;
    int xcd = lane & 7;
    for (int b = 0; b < nb; b++){
      int idx = xcd * SLOTS + sbase + b;
      if (sbase + b < SLOTS){
        bm_e[idx] = lane; bm_start[idx] = start + b * BM; bm_end[idx] = start + c;
      }
    }
  }
}

// ---------------- scatter: block-aggregated chunk reservation, LDS ranks
__global__ __launch_bounds__(256) void scatter_kernel(const int* __restrict__ top_idx,
                                                      const float* __restrict__ top_w,
                                                      int* __restrict__ cursor,
                                                      int* __restrict__ pair_tok,
                                                      float* __restrict__ pair_w,
                                                      int* __restrict__ pair_slot){
  __shared__ int hist[16], base[16], rank[16];
  int tid = threadIdx.x;
  if (tid < 16){ hist[tid] = 0; rank[tid] = 0; }
  __syncthreads();
  int t = blockIdx.x * 256 + tid;
  int e0 = top_idx[t * 2], e1 = top_idx[t * 2 + 1];
  float w0 = top_w[t * 2], w1 = top_w[t * 2 + 1];
  atomicAdd(&hist[e0], 1); atomicAdd(&hist[e1], 1);
  __syncthreads();
  if (tid < 16) base[tid] = atomicAdd(&cursor[tid], hist[tid]);
  __syncthreads();
  int r0 = atomicAdd(&rank[e0], 1);
  int p0 = base[e0] + r0;
  pair_tok[p0] = t; pair_w[p0] = w0; pair_slot[t * 2] = p0;
  int r1 = atomicAdd(&rank[e1], 1);
  int p1 = base[e1] + r1;
  pair_tok[p1] = t; pair_w[p1] = w1; pair_slot[t * 2 + 1] = p1;
}

// ---------------- fused 2-layer expert MLP, 128 pairs/block, 8 waves
// x rows in registers; W1/W2 chunk tiles LDS-staged via global_load_lds
// (pre-swizzled source, linear dest); double-buffered; 1 barrier/chunk;
// h tile is wave-private (no layer barrier). Expert->XCD affinity.
__global__ __launch_bounds__(512, 2) void moe_gemm_kernel(
    const unsigned short* __restrict__ x_bf,   // [B][256]
    const unsigned short* __restrict__ W1t,    // [E][512][256]  (n-major, 512B rows)
    const unsigned short* __restrict__ W2t,    // [E][256][512]  (n-major, 1024B rows)
    const float* __restrict__ b1,              // [E][512]
    const float* __restrict__ b2,              // [E][256]
    const int* __restrict__ pair_tok, const float* __restrict__ pair_w,
    const int* __restrict__ bm_e, const int* __restrict__ bm_start,
    const int* __restrict__ bm_end,
    unsigned short* __restrict__ ypair){       // [65536][256] bf16
  int xcd = blockIdx.x & 7, slot = blockIdx.x >> 3;
  int bmi = xcd * SLOTS + slot;
  int e = bm_e[bmi];
  if (e < 0) return;
  int rs = bm_start[bmi], re = bm_end[bmi];

  __shared__ unsigned short w1s[2][64 * 256];   // 2x32KB [hid][k], swizzled
  __shared__ unsigned short w2s[2][256 * 64];   // 2x32KB [out][k], swizzled
  __shared__ unsigned short hsm[8][16 * 64];    // 16KB, per-wave [m][k], swizzled

  int tid = threadIdx.x, wid = tid >> 6, lane = tid & 63, lr = lane & 15, lh = lane >> 4;
  const char* gW1 = (const char*)(W1t + (size_t)e * DHID * DIN);
  const char* gW2 = (const char*)(W2t + (size_t)e * DOUT * DHID);

  // ---- x rows -> registers (once per block; scattered but amortized)
  int g = rs + 16 * wid + lr;
  int gc = g < re ? g : (re - 1);
  int tok = pair_tok[gc];
  bf16x8 xr[8];
  const unsigned short* xrow = x_bf + (size_t)tok * DIN + lh * 8;
#pragma unroll
  for (int ks = 0; ks < 8; ks++) xr[ks] = *(const bf16x8*)(xrow + ks * 32);

  // ---- staging: waves 0-3 stage W1 chunk, waves 4-7 stage W2 chunk
  auto stage = [&](int c, int sl){
    if (wid < 4){
      const char* base = gW1 + (size_t)c * 32768;          // 64 rows x 512B
      char* lds = (char*)w1s[sl];
#pragma unroll
      for (int i = 0; i < 8; i++){
        int boff = wid * 8192 + i * 1024;
        int off = boff + lane * 16;
        int row = off >> 9;
        gload16(base + (off ^ ((row & 7) << 4)), lds + boff);
      }
    } else {
      const char* base = gW2 + (size_t)c * 128;            // col offset within 1024B rows
      char* lds = (char*)w2s[sl];
#pragma unroll
      for (int i = 0; i < 8; i++){
        int boff = (wid - 4) * 8192 + i * 1024;
        int off = boff + lane * 16;
        int row = off >> 7;                                // tile row (out idx), 128B
        int inrow = off & 127;
        gload16(base + (size_t)row * 1024 + (inrow ^ ((row & 7) << 4)), lds + boff);
      }
    }
  };

  stage(0, 0);

  f32x4 acc[16];
#pragma unroll
  for (int i = 0; i < 16; i++) acc[i] = (f32x4){0.f, 0.f, 0.f, 0.f};

  char* hsb = (char*)hsm[wid];
  __syncthreads();   // chunk 0 staged (drains vmcnt)

  for (int c = 0; c < 8; c++){
    int sl = c & 1;
    if (c < 7) stage(c + 1, sl ^ 1);

    float b1v[4];
#pragma unroll
    for (int nt = 0; nt < 4; nt++) b1v[nt] = b1[e * DHID + c * 64 + nt * 16 + lr];

    // ---- phase A: h = x @ W1c  (A from regs, B from LDS)
    f32x4 hacc[4];
#pragma unroll
    for (int i = 0; i < 4; i++) hacc[i] = (f32x4){0.f, 0.f, 0.f, 0.f};
    const char* w1b = (const char*)w1s[sl];
#pragma unroll
    for (int ks = 0; ks < 8; ks++){
#pragma unroll
      for (int nt = 0; nt < 4; nt++){
        int row = nt * 16 + lr;
        int kk = ks * 32 + lh * 8;
        bf16x8 b = *(const bf16x8*)(w1b + ((row * 512 + kk * 2) ^ ((row & 7) << 4)));
        hacc[nt] = __builtin_amdgcn_mfma_f32_16x16x32_bf16(xr[ks], b, hacc[nt], 0, 0, 0);
      }
    }

    // ---- relu(h+b1) -> wave-private hs (no barrier needed)
#pragma unroll
    for (int nt = 0; nt < 4; nt++)
#pragma unroll
      for (int r = 0; r < 4; r++){
        int hrow = lh * 4 + r;
        int hcol = nt * 16 + lr;
        float v = fmaxf(hacc[nt][r] + b1v[nt], 0.f);
        *(unsigned short*)(hsb + ((hrow * 128 + hcol * 2) ^ ((hrow & 7) << 4))) = f2bf(v);
      }

    // ---- phase B: y += h @ W2c
    bf16x8 ha[2];
#pragma unroll
    for (int k2 = 0; k2 < 2; k2++)
      ha[k2] = *(const bf16x8*)(hsb + ((lr * 128 + (k2 * 32 + lh * 8) * 2) ^ ((lr & 7) << 4)));
    const char* w2b = (const char*)w2s[sl];
#pragma unroll
    for (int nt = 0; nt < 16; nt++){
      int row = nt * 16 + lr;
#pragma unroll
      for (int k2 = 0; k2 < 2; k2++){
        bf16x8 b = *(const bf16x8*)(w2b + ((row * 128 + (k2 * 32 + lh * 8) * 2) ^ ((row & 7) << 4)));
        acc[nt] = __builtin_amdgcn_mfma_f32_16x16x32_bf16(ha[k2], b, acc[nt], 0, 0, 0);
      }
    }
    if (c < 7) __syncthreads();   // next chunk staged; protects W slots
  }

  // ---- epilogue: fold gate weight + b2, store per-pair bf16 rows
  float wrow[4]; int grow[4];
#pragma unroll
  for (int r = 0; r < 4; r++){
    int gg = rs + 16 * wid + lh * 4 + r;
    grow[r] = gg;
    wrow[r] = (gg < re) ? pair_w[gg] : 0.f;
  }
#pragma unroll
  for (int nt = 0; nt < 16; nt++){
    int col = nt * 16 + lr;
    float b2v = b2[e * DOUT + col];
#pragma unroll
    for (int r = 0; r < 4; r++){
      if (grow[r] < re)
        ypair[(size_t)grow[r] * DOUT + col] = f2bf(wrow[r] * (acc[nt][r] + b2v));
    }
  }
}

// ---------------- combine two pair rows per token
__global__ __launch_bounds__(256) void combine_kernel(const unsigned short* __restrict__ yp,
                                                      const int* __restrict__ pair_slot,
                                                      float* __restrict__ out){
  int idx = blockIdx.x * 256 + threadIdx.x;
  int t = idx >> 6;
  int c4 = (idx & 63) << 2;
  int s0 = pair_slot[t * 2], s1 = pair_slot[t * 2 + 1];
  ushort4 a = *(const ushort4*)(yp + (size_t)s0 * DOUT + c4);
  ushort4 b = *(const ushort4*)(yp + (size_t)s1 * DOUT + c4);
  float4 o;
  o.x = bf2f(a.x) + bf2f(b.x);
  o.y = bf2f(a.y) + bf2f(b.y);
  o.z = bf2f(a.z) + bf2f(b.z);
  o.w = bf2f(a.w) + bf2f(b.w);
  *(float4*)(out + (size_t)t * DOUT + c4) = o;
}

extern "C" void kernel_launch(void* const* d_in, const int* in_sizes, int n_in,
                              void* d_out, int out_size, void* d_ws, size_t ws_size,
                              hipStream_t stream){
  (void)in_sizes; (void)n_in; (void)out_size; (void)ws_size;
  const float* x  = (const float*)d_in[0];
  const float* Wg = (const float*)d_in[1];
  const float* bg = (const float*)d_in[2];
  const float* W1 = (const float*)d_in[3];
  const float* b1 = (const float*)d_in[4];
  const float* W2 = (const float*)d_in[5];
  const float* b2 = (const float*)d_in[6];
  float* out = (float*)d_out;
  char* ws = (char*)d_ws;

  unsigned short* x_bf  = (unsigned short*)(ws);                 // 16,777,216
  unsigned short* W1t   = (unsigned short*)(ws + 16777216);      //  4,194,304
  unsigned short* W2t   = (unsigned short*)(ws + 20971520);      //  4,194,304
  unsigned short* ypair = (unsigned short*)(ws + 25165824);      // 33,554,432
  int*   top_idx  = (int*)  (ws + 58720256);
  float* top_w    = (float*)(ws + 58982400);
  int*   pair_tok = (int*)  (ws + 59244544);
  float* pair_w   = (float*)(ws + 59506688);
  int*   pair_slot= (int*)  (ws + 59768832);
  int*   counts   = (int*)  (ws + 60030976);
  int*   offsets  = (int*)  (ws + 60031040);
  int*   cursor   = (int*)  (ws + 60031104);
  int*   bm_e     = (int*)  (ws + 60031232);   // 640 ints
  int*   bm_start = (int*)  (ws + 60035584);   // 640 ints
  int*   bm_end   = (int*)  (ws + 60039936);   // 640 ints

  hipMemsetAsync(counts, 0, 64, stream);
  transpose_cvt<<<dim3(16, 8, 16), 256, 0, stream>>>(W1, W1t, 256, 512);
  transpose_cvt<<<dim3(8, 16, 16), 256, 0, stream>>>(W2, W2t, 512, 256);
  gating_kernel<<<512, 256, 0, stream>>>(x, Wg, bg, x_bf, top_idx, top_w, counts);
  prefix_kernel<<<1, 64, 0, stream>>>(counts, offsets, cursor, bm_e, bm_start, bm_end);
  scatter_kernel<<<128, 256, 0, stream>>>(top_idx, top_w, cursor, pair_tok, pair_w, pair_slot);
  moe_gemm_kernel<<<8 * SLOTS, 512, 0, stream>>>(x_bf, W1t, W2t, b1, b2, pair_tok, pair_w,
                                                 bm_e, bm_start, bm_end, ypair);
  combine_kernel<<<8192, 256, 0, stream>>>(ypair, pair_slot, out);
}